// Round 6
// baseline (404.050 us; speedup 1.0000x reference)
//
#include <hip/hip_runtime.h>

#define T_DIM 1024
#define D_DIM 512
#define M_CODES 2048
#define NT 32768            // 32*1024 query rows
#define TOTAL 16777216      // NT*D_DIM

typedef _Float16 h2 __attribute__((ext_vector_type(2)));
typedef _Float16 h4 __attribute__((ext_vector_type(4)));
typedef _Float16 h8 __attribute__((ext_vector_type(8)));
typedef float f32x4 __attribute__((ext_vector_type(4)));
typedef unsigned int u32;

// ---- workspace layout (bytes) ----
#define WS_MU    0                        // 16384 f32
#define WS_S     65536                    // 16384 f32
#define WS_CZ    131072                   // 32768 f32
#define WS_CE    262144                   // 2048 f32
#define WS_KEYS  270336                   // 32768 u64
#define WS_EH    532480                   // 2048*512 f16
#define WS_EL    (532480 + 2097152)       // 2048*512 f16
#define WS_HIST  (532480 + 4194304)       // 2048 u32
#define WS_LPART (WS_HIST + 8192)         // 8192 f32 per-block loss partials

// per-buffer LDS: Ah 16K | Al 16K | Bh 8K | Bl 8K = 48KB; 3 buffers = 144KB
#define BUF_BYTES 49152

// async global->LDS, 16B per lane; dst must be wave-uniform (HW adds lane*16)
__device__ __forceinline__ void gload16(const void* g, void* l) {
    __builtin_amdgcn_global_load_lds(
        (const __attribute__((address_space(1))) u32*)g,
        (__attribute__((address_space(3))) u32*)l, 16, 0, 0);
}

__device__ __forceinline__ float block_reduce_sum_256(float v) {
    #pragma unroll
    for (int s = 32; s; s >>= 1) v += __shfl_xor(v, s, 64);
    __shared__ float ls[4];
    int w = threadIdx.x >> 6;
    if ((threadIdx.x & 63) == 0) ls[w] = v;
    __syncthreads();
    float r = (ls[0] + ls[1]) + (ls[2] + ls[3]);
    __syncthreads();
    return r;
}

struct Split { _Float16 hi, lo; };
// v = hi + lo*2^-11 with hi,lo fp16 (lo pre-scaled by 2^11 to stay normal)
__device__ __forceinline__ Split split16(float v) {
    Split r;
    _Float16 h = (_Float16)v;
    float res = v - (float)h;            // exact (Sterbenz)
    r.hi = h;
    r.lo = (_Float16)(res * 2048.0f);    // scale exact
    return r;
}

// ---- instance-norm stats over T per (n,d): mu, s=std+eps ----
__global__ void stats_kernel(const float* __restrict__ x,
                             float* __restrict__ mu_o, float* __restrict__ s_o) {
    int n = blockIdx.y;
    int lane = threadIdx.x & 63;
    int d = blockIdx.x * 64 + lane;
    int tg = threadIdx.x >> 6;
    const float* xp = x + (size_t)n * (T_DIM * D_DIM) + d;
    float sum = 0.f, sq = 0.f;
    int t0 = tg * 256;
    for (int it = 0; it < 256; ++it) {
        float v = xp[(size_t)(t0 + it) * D_DIM];
        sum += v; sq += v * v;
    }
    __shared__ float ssum[4][64], ssq[4][64];
    ssum[tg][lane] = sum;
    ssq[tg][lane] = sq;
    __syncthreads();
    if (threadIdx.x < 64) {
        int l = threadIdx.x;
        float s1 = (ssum[0][l] + ssum[1][l]) + (ssum[2][l] + ssum[3][l]);
        float q1 = (ssq[0][l] + ssq[1][l]) + (ssq[2][l] + ssq[3][l]);
        float mu = s1 * (1.0f / 1024.0f);
        float var = (q1 - 1024.0f * mu * mu) * (1.0f / 1023.0f);
        var = fmaxf(var, 0.0f);
        float sd = sqrtf(var) + 1e-5f;
        int nd = n * D_DIM + blockIdx.x * 64 + l;
        mu_o[nd] = mu; s_o[nd] = sd;
    }
}

// ---- codebook prep: emb_n split to f16 hi/lo, ce = sum(emb_n^2) ----
__global__ void codebook_kernel(const float* __restrict__ emb,
                                _Float16* __restrict__ eh, _Float16* __restrict__ el,
                                float* __restrict__ ce) {
    int j = blockIdx.x;
    int d = threadIdx.x * 2;
    float2 e = *(const float2*)&emb[(size_t)j * D_DIM + d];
    float sq = e.x * e.x + e.y * e.y;
    float norm2 = block_reduce_sum_256(sq);
    float den = sqrtf(norm2) + 1e-4f;
    float en0 = e.x / den, en1 = e.y / den;
    Split s0 = split16(en0), s1 = split16(en1);
    h2 hv, lv;
    hv[0] = s0.hi; hv[1] = s1.hi;
    lv[0] = s0.lo; lv[1] = s1.lo;
    *(h2*)&eh[(size_t)j * D_DIM + d] = hv;
    *(h2*)&el[(size_t)j * D_DIM + d] = lv;
    float cep = en0 * en0 + en1 * en1;
    float cesum = block_reduce_sum_256(cep);
    if (threadIdx.x == 0) ce[j] = cesum;
}

// ---- z = (x-mu)/s exactly like ref; write f16 split + cz = ||z||^2 ----
__global__ void cz_split_kernel(const float* __restrict__ x, const float* __restrict__ mu,
                                const float* __restrict__ s, float* __restrict__ cz,
                                _Float16* __restrict__ zh, _Float16* __restrict__ zl) {
    int i = blockIdx.x * 4 + (threadIdx.x >> 6);
    int lane = threadIdx.x & 63;
    int n = i >> 10;
    const float* xp = x + (size_t)i * D_DIM;
    const float* mp = mu + n * D_DIM;
    const float* sp = s + n * D_DIM;
    float acc = 0.f;
    #pragma unroll
    for (int c = 0; c < 2; ++c) {
        int d = c * 256 + lane * 4;
        float4 xv = *(const float4*)&xp[d];
        float4 mv = *(const float4*)&mp[d];
        float4 sv = *(const float4*)&sp[d];
        float z0 = (xv.x - mv.x) / sv.x;
        float z1 = (xv.y - mv.y) / sv.y;
        float z2 = (xv.z - mv.z) / sv.z;
        float z3 = (xv.w - mv.w) / sv.w;
        Split s0 = split16(z0), s1 = split16(z1), s2 = split16(z2), s3 = split16(z3);
        h4 hv, lv;
        hv[0] = s0.hi; hv[1] = s1.hi; hv[2] = s2.hi; hv[3] = s3.hi;
        lv[0] = s0.lo; lv[1] = s1.lo; lv[2] = s2.lo; lv[3] = s3.lo;
        *(h4*)&zh[(size_t)i * D_DIM + d] = hv;
        *(h4*)&zl[(size_t)i * D_DIM + d] = lv;
        acc += z0 * z0 + z1 * z1 + z2 * z2 + z3 * z3;
    }
    #pragma unroll
    for (int sft = 32; sft; sft >>= 1) acc += __shfl_xor(acc, sft, 64);
    if (lane == 0) cz[i] = acc;
}

// ---- MFMA fp16-split GEMM + argmin, 3-deep pipeline, counted vmcnt ----
// Tile 256(M)x128(N), BK=32, 8 waves (4Mx2N), 3 LDS buffers, 1 block/CU.
// Swizzle: LDS slot s of row r holds global slot s ^ ((r>>1)&3).
__global__ __launch_bounds__(512, 2) void gemm_argmin(
    const _Float16* __restrict__ zh, const _Float16* __restrict__ zl,
    const _Float16* __restrict__ eh, const _Float16* __restrict__ el,
    const float* __restrict__ ce, const float* __restrict__ cz,
    unsigned long long* __restrict__ keys) {
    extern __shared__ __align__(16) char lds_raw[];
    int tid = threadIdx.x;
    int bid = blockIdx.x;
    int swz = (bid & 7) * 256 + (bid >> 3);   // XCD-chunked, bijective (2048%8==0)
    int n0 = (swz & 15) * 128;                // code tile (16 n-tiles)
    int m0 = (swz >> 4) * 256;                // query-row tile (128 m-tiles)

    f32x4 acc0[4][4], acc1[4][4];
    #pragma unroll
    for (int a = 0; a < 4; ++a)
        #pragma unroll
        for (int b = 0; b < 4; ++b) { acc0[a][b] = (f32x4)0.0f; acc1[a][b] = (f32x4)0.0f; }

    int w = tid >> 6, l = tid & 63;
    int wm = (w >> 1) * 64;                   // 4 M-groups of 64 (256 rows)
    int wn = (w & 1) * 64;                    // 2 N-groups of 64 (128 rows)
    int fr = l & 15, fg = l >> 4;

    // staging geometry (per wave, per buffer: 6 gload16 = 6KB)
    // A: rows 32w..32w+31 (2 instrs x 16 rows x 2 arrays); B: rows 16w..16w+15
    #define STAGE(buf, kc) do {                                                   \
        char* sbase = lds_raw + (buf) * BUF_BYTES;                                \
        h8* SAh = (h8*)sbase;            h8* SAl = (h8*)(sbase + 16384);          \
        h8* SBh = (h8*)(sbase + 32768);  h8* SBl = (h8*)(sbase + 40960);          \
        _Pragma("unroll")                                                         \
        for (int q = 0; q < 2; ++q) {                                             \
            int rA = 32 * w + 16 * q + (l >> 2);                                  \
            int cA = (((l & 3) ^ ((rA >> 1) & 3)) << 3);                          \
            size_t oa = (size_t)(m0 + rA) * D_DIM + (kc) + cA;                    \
            gload16(zh + oa, &SAh[(32 * w + 16 * q) * 4]);                        \
            gload16(zl + oa, &SAl[(32 * w + 16 * q) * 4]);                        \
        }                                                                         \
        int rB = 16 * w + (l >> 2);                                               \
        int cB = (((l & 3) ^ ((rB >> 1) & 3)) << 3);                              \
        size_t ob = (size_t)(n0 + rB) * D_DIM + (kc) + cB;                        \
        gload16(eh + ob, &SBh[16 * w * 4]);                                       \
        gload16(el + ob, &SBl[16 * w * 4]);                                       \
    } while (0)

    STAGE(0, 0);
    STAGE(1, 32);
    asm volatile("s_waitcnt vmcnt(6)" ::: "memory");   // buf0's 6 landed
    __builtin_amdgcn_s_barrier();
    __builtin_amdgcn_sched_barrier(0);

    int rd = 0;
    for (int t = 0; t < 16; ++t) {
        int wr = rd + 2; if (wr >= 3) wr -= 3;
        if (t < 14) STAGE(wr, (t + 2) * 32);

        char* rbase = lds_raw + rd * BUF_BYTES;
        h8* RAh = (h8*)rbase;            h8* RAl = (h8*)(rbase + 16384);
        h8* RBh = (h8*)(rbase + 32768);  h8* RBl = (h8*)(rbase + 40960);
        h8 ah[4], al[4], bh[4], bl[4];
        #pragma unroll
        for (int i = 0; i < 4; ++i) {
            int ra = wm + i * 16 + fr;
            int sa = ra * 4 + (fg ^ ((ra >> 1) & 3));
            ah[i] = RAh[sa];
            al[i] = RAl[sa];
            int rb = wn + i * 16 + fr;
            int sb = rb * 4 + (fg ^ ((rb >> 1) & 3));
            bh[i] = RBh[sb];
            bl[i] = RBl[sb];
        }
        __builtin_amdgcn_s_setprio(1);
        #pragma unroll
        for (int mb = 0; mb < 4; ++mb)
            #pragma unroll
            for (int nb = 0; nb < 4; ++nb) {
                acc0[mb][nb] = __builtin_amdgcn_mfma_f32_16x16x32_f16(ah[mb], bh[nb], acc0[mb][nb], 0, 0, 0);
                acc1[mb][nb] = __builtin_amdgcn_mfma_f32_16x16x32_f16(ah[mb], bl[nb], acc1[mb][nb], 0, 0, 0);
                acc1[mb][nb] = __builtin_amdgcn_mfma_f32_16x16x32_f16(al[mb], bh[nb], acc1[mb][nb], 0, 0, 0);
            }
        __builtin_amdgcn_s_setprio(0);

        if (t < 15) {
            // counted wait: oldest 6 (next read buffer) done; newer 6 in flight
            if (t < 14) asm volatile("s_waitcnt vmcnt(6)" ::: "memory");
            else        asm volatile("s_waitcnt vmcnt(0)" ::: "memory");
            __builtin_amdgcn_s_barrier();
            __builtin_amdgcn_sched_barrier(0);
        }
        if (++rd == 3) rd = 0;
    }
    #undef STAGE

    // epilogue: dist = (ce+cz) - 2*dot, dot = acc0 + acc1*2^-11
    #pragma unroll
    for (int mb = 0; mb < 4; ++mb) {
        #pragma unroll
        for (int r = 0; r < 4; ++r) {
            int q = m0 + wm + mb * 16 + fg * 4 + r;
            float czq = cz[q];
            unsigned long long best = ~0ULL;
            #pragma unroll
            for (int nb = 0; nb < 4; ++nb) {
                int j = n0 + wn + nb * 16 + fr;
                float dotv = acc0[mb][nb][r] + acc1[mb][nb][r] * (1.0f / 2048.0f);
                float dist = (ce[j] + czq) - 2.0f * dotv;
                unsigned long long key =
                    ((unsigned long long)__float_as_uint(dist) << 32) | (unsigned)j;
                if (key < best) best = key;
            }
            #pragma unroll
            for (int sft = 1; sft < 16; sft <<= 1) {
                unsigned long long o = __shfl_xor(best, sft, 64);
                if (o < best) best = o;
            }
            if (fr == 0) atomicMin(keys + q, best);
        }
    }
}

// ---- gather + STE output + loss partials + histogram (1 wave per row) ----
__global__ void output_kernel(const float* __restrict__ x, const float* __restrict__ mu,
                              const float* __restrict__ s, const float* __restrict__ emb,
                              const unsigned long long* __restrict__ keys,
                              float* __restrict__ out, float* __restrict__ loss_part,
                              unsigned* __restrict__ hist) {
    int i = blockIdx.x * 4 + (threadIdx.x >> 6);
    int lane = threadIdx.x & 63;
    int n = i >> 10;
    unsigned idx = (unsigned)(keys[i] & 0xFFFFFFFFULL);
    float lsum = 0.f;
    #pragma unroll
    for (int c = 0; c < 2; ++c) {
        int d = c * 256 + lane * 4;
        float4 xv = *(const float4*)&x[(size_t)i * D_DIM + d];
        float4 mv = *(const float4*)&mu[n * D_DIM + d];
        float4 sv = *(const float4*)&s[n * D_DIM + d];
        float4 ev = *(const float4*)&emb[(size_t)idx * D_DIM + d];
        float z0 = (xv.x - mv.x) / sv.x;
        float z1 = (xv.y - mv.y) / sv.y;
        float z2 = (xv.z - mv.z) / sv.z;
        float z3 = (xv.w - mv.w) / sv.w;
        float o0 = ((z0 + (ev.x - z0)) + ev.x) * 0.5f;
        float o1 = ((z1 + (ev.y - z1)) + ev.y) * 0.5f;
        float o2 = ((z2 + (ev.z - z2)) + ev.z) * 0.5f;
        float o3 = ((z3 + (ev.w - z3)) + ev.w) * 0.5f;
        *(float4*)&out[(size_t)i * D_DIM + d] = make_float4(o0, o1, o2, o3);
        lsum += (z0 - ev.x) * (z0 - ev.x) + (z1 - ev.y) * (z1 - ev.y)
              + (z2 - ev.z) * (z2 - ev.z) + (z3 - ev.w) * (z3 - ev.w);
    }
    #pragma unroll
    for (int sft = 32; sft; sft >>= 1) lsum += __shfl_xor(lsum, sft, 64);
    __shared__ float ls[4];
    if (lane == 0) {
        ls[threadIdx.x >> 6] = lsum;
        atomicAdd(&hist[idx], 1u);   // scattered over 2048 bins: cheap
    }
    __syncthreads();
    if (threadIdx.x == 0)
        loss_part[blockIdx.x] = (ls[0] + ls[1]) + (ls[2] + ls[3]);
}

// ---- scalars: loss mean (from partials) + perplexity ----
__global__ void final_kernel(const unsigned* __restrict__ hist,
                             const float* __restrict__ loss_part, float* __restrict__ out) {
    float h = 0.f;
    for (int b = threadIdx.x; b < M_CODES; b += 256) {
        float p = (float)hist[b] * (1.0f / 32768.0f);
        h += p * logf(p + 1e-10f);
    }
    h = block_reduce_sum_256(h);
    float lsum = 0.f;
    for (int b = threadIdx.x; b < NT / 4; b += 256) lsum += loss_part[b];
    lsum = block_reduce_sum_256(lsum);
    if (threadIdx.x == 0) {
        out[TOTAL] = lsum * (1.0f / 16777216.0f);
        out[TOTAL + 1] = expf(-h);
    }
}

extern "C" void kernel_launch(void* const* d_in, const int* in_sizes, int n_in,
                              void* d_out, int out_size, void* d_ws, size_t ws_size,
                              hipStream_t stream) {
    (void)in_sizes; (void)n_in; (void)out_size; (void)ws_size;
    const float* x = (const float*)d_in[0];
    const float* emb = (const float*)d_in[1];
    float* out = (float*)d_out;
    char* ws = (char*)d_ws;
    float* mu   = (float*)(ws + WS_MU);
    float* s    = (float*)(ws + WS_S);
    float* cz   = (float*)(ws + WS_CZ);
    float* ce   = (float*)(ws + WS_CE);
    unsigned long long* keys = (unsigned long long*)(ws + WS_KEYS);
    _Float16* eh = (_Float16*)(ws + WS_EH);
    _Float16* el = (_Float16*)(ws + WS_EL);
    unsigned* hist = (unsigned*)(ws + WS_HIST);
    float* loss_part = (float*)(ws + WS_LPART);
    // z fp16 split staged in d_out (64MB exactly), overwritten by output_kernel
    _Float16* zh = (_Float16*)d_out;
    _Float16* zl = zh + TOTAL;

    // allow 144KB dynamic LDS (idempotent; not a stream op -> capture-safe)
    (void)hipFuncSetAttribute((const void*)gemm_argmin,
                              hipFuncAttributeMaxDynamicSharedMemorySize,
                              3 * BUF_BYTES);

    (void)hipMemsetAsync(ws + WS_KEYS, 0xFF, 262144, stream);
    (void)hipMemsetAsync(ws + WS_HIST, 0x00, 8192, stream);

    stats_kernel<<<dim3(8, 32), 256, 0, stream>>>(x, mu, s);
    codebook_kernel<<<M_CODES, 256, 0, stream>>>(emb, eh, el, ce);
    cz_split_kernel<<<NT / 4, 256, 0, stream>>>(x, mu, s, cz, zh, zl);
    gemm_argmin<<<2048, 512, 3 * BUF_BYTES, stream>>>(zh, zl, eh, el, ce, cz, keys);
    output_kernel<<<NT / 4, 256, 0, stream>>>(x, mu, s, emb, keys, out, loss_part, hist);
    final_kernel<<<1, 256, 0, stream>>>(hist, loss_part, out);
}

// Round 7
// 393.330 us; speedup vs baseline: 1.0273x; 1.0273x over previous
//
#include <hip/hip_runtime.h>

#define T_DIM 1024
#define D_DIM 512
#define M_CODES 2048
#define NT 32768            // 32*1024 query rows
#define TOTAL 16777216      // NT*D_DIM

typedef _Float16 h2 __attribute__((ext_vector_type(2)));
typedef _Float16 h4 __attribute__((ext_vector_type(4)));
typedef _Float16 h8 __attribute__((ext_vector_type(8)));
typedef float f32x4 __attribute__((ext_vector_type(4)));
typedef unsigned int u32;

// ---- workspace layout (bytes) ----
#define WS_MU    0                        // 16384 f32
#define WS_S     65536                    // 16384 f32
#define WS_CZ    131072                   // 32768 f32
#define WS_CE    262144                   // 2048 f32
#define WS_KEYS  270336                   // 32768 u64
#define WS_EH    532480                   // 2048*512 f16
#define WS_EL    (532480 + 2097152)       // 2048*512 f16
#define WS_HIST  (532480 + 4194304)       // 2048 u32
#define WS_LPART (WS_HIST + 8192)         // 8192 f32 per-block loss partials

// per-buffer LDS: Ah 16K | Al 16K | Bh 8K | Bl 8K = 48KB; 3 buffers = 144KB
#define BUF_BYTES 49152

// async global->LDS, 16B per lane; dst must be wave-uniform (HW adds lane*16)
__device__ __forceinline__ void gload16(const void* g, void* l) {
    __builtin_amdgcn_global_load_lds(
        (const __attribute__((address_space(1))) u32*)g,
        (__attribute__((address_space(3))) u32*)l, 16, 0, 0);
}

// raw LDS read, byte address in AS3
__device__ __forceinline__ h8 ds_read_h8(u32 addr) {
    h8 v;
    asm volatile("ds_read_b128 %0, %1" : "=v"(v) : "v"(addr));
    return v;
}

#define LGKM(n) do { asm volatile("s_waitcnt lgkmcnt(" #n ")" ::: "memory"); \
                     __builtin_amdgcn_sched_barrier(0); } while (0)

__device__ __forceinline__ float block_reduce_sum_256(float v) {
    #pragma unroll
    for (int s = 32; s; s >>= 1) v += __shfl_xor(v, s, 64);
    __shared__ float ls[4];
    int w = threadIdx.x >> 6;
    if ((threadIdx.x & 63) == 0) ls[w] = v;
    __syncthreads();
    float r = (ls[0] + ls[1]) + (ls[2] + ls[3]);
    __syncthreads();
    return r;
}

struct Split { _Float16 hi, lo; };
// v = hi + lo*2^-11 with hi,lo fp16 (lo pre-scaled by 2^11 to stay normal)
__device__ __forceinline__ Split split16(float v) {
    Split r;
    _Float16 h = (_Float16)v;
    float res = v - (float)h;            // exact (Sterbenz)
    r.hi = h;
    r.lo = (_Float16)(res * 2048.0f);    // scale exact
    return r;
}

// ---- instance-norm stats over T per (n,d): mu, s=std+eps ----
__global__ void stats_kernel(const float* __restrict__ x,
                             float* __restrict__ mu_o, float* __restrict__ s_o) {
    int n = blockIdx.y;
    int lane = threadIdx.x & 63;
    int d = blockIdx.x * 64 + lane;
    int tg = threadIdx.x >> 6;
    const float* xp = x + (size_t)n * (T_DIM * D_DIM) + d;
    float sum = 0.f, sq = 0.f;
    int t0 = tg * 256;
    for (int it = 0; it < 256; ++it) {
        float v = xp[(size_t)(t0 + it) * D_DIM];
        sum += v; sq += v * v;
    }
    __shared__ float ssum[4][64], ssq[4][64];
    ssum[tg][lane] = sum;
    ssq[tg][lane] = sq;
    __syncthreads();
    if (threadIdx.x < 64) {
        int l = threadIdx.x;
        float s1 = (ssum[0][l] + ssum[1][l]) + (ssum[2][l] + ssum[3][l]);
        float q1 = (ssq[0][l] + ssq[1][l]) + (ssq[2][l] + ssq[3][l]);
        float mu = s1 * (1.0f / 1024.0f);
        float var = (q1 - 1024.0f * mu * mu) * (1.0f / 1023.0f);
        var = fmaxf(var, 0.0f);
        float sd = sqrtf(var) + 1e-5f;
        int nd = n * D_DIM + blockIdx.x * 64 + l;
        mu_o[nd] = mu; s_o[nd] = sd;
    }
}

// ---- codebook prep: emb_n split to f16 hi/lo, ce = sum(emb_n^2) ----
__global__ void codebook_kernel(const float* __restrict__ emb,
                                _Float16* __restrict__ eh, _Float16* __restrict__ el,
                                float* __restrict__ ce) {
    int j = blockIdx.x;
    int d = threadIdx.x * 2;
    float2 e = *(const float2*)&emb[(size_t)j * D_DIM + d];
    float sq = e.x * e.x + e.y * e.y;
    float norm2 = block_reduce_sum_256(sq);
    float den = sqrtf(norm2) + 1e-4f;
    float en0 = e.x / den, en1 = e.y / den;
    Split s0 = split16(en0), s1 = split16(en1);
    h2 hv, lv;
    hv[0] = s0.hi; hv[1] = s1.hi;
    lv[0] = s0.lo; lv[1] = s1.lo;
    *(h2*)&eh[(size_t)j * D_DIM + d] = hv;
    *(h2*)&el[(size_t)j * D_DIM + d] = lv;
    float cep = en0 * en0 + en1 * en1;
    float cesum = block_reduce_sum_256(cep);
    if (threadIdx.x == 0) ce[j] = cesum;
}

// ---- z = (x-mu)/s exactly like ref; write f16 split + cz = ||z||^2 ----
__global__ void cz_split_kernel(const float* __restrict__ x, const float* __restrict__ mu,
                                const float* __restrict__ s, float* __restrict__ cz,
                                _Float16* __restrict__ zh, _Float16* __restrict__ zl) {
    int i = blockIdx.x * 4 + (threadIdx.x >> 6);
    int lane = threadIdx.x & 63;
    int n = i >> 10;
    const float* xp = x + (size_t)i * D_DIM;
    const float* mp = mu + n * D_DIM;
    const float* sp = s + n * D_DIM;
    float acc = 0.f;
    #pragma unroll
    for (int c = 0; c < 2; ++c) {
        int d = c * 256 + lane * 4;
        float4 xv = *(const float4*)&xp[d];
        float4 mv = *(const float4*)&mp[d];
        float4 sv = *(const float4*)&sp[d];
        float z0 = (xv.x - mv.x) / sv.x;
        float z1 = (xv.y - mv.y) / sv.y;
        float z2 = (xv.z - mv.z) / sv.z;
        float z3 = (xv.w - mv.w) / sv.w;
        Split s0 = split16(z0), s1 = split16(z1), s2 = split16(z2), s3 = split16(z3);
        h4 hv, lv;
        hv[0] = s0.hi; hv[1] = s1.hi; hv[2] = s2.hi; hv[3] = s3.hi;
        lv[0] = s0.lo; lv[1] = s1.lo; lv[2] = s2.lo; lv[3] = s3.lo;
        *(h4*)&zh[(size_t)i * D_DIM + d] = hv;
        *(h4*)&zl[(size_t)i * D_DIM + d] = lv;
        acc += z0 * z0 + z1 * z1 + z2 * z2 + z3 * z3;
    }
    #pragma unroll
    for (int sft = 32; sft; sft >>= 1) acc += __shfl_xor(acc, sft, 64);
    if (lane == 0) cz[i] = acc;
}

// ---- MFMA fp16-split GEMM + argmin, 3-deep pipeline + 4-phase interleave ----
// Tile 256(M)x128(N), BK=32, 8 waves (4Mx2N), 3 LDS buffers.
// Swizzle: LDS slot s of row r holds global slot s ^ ((r>>1)&3).
__global__ __launch_bounds__(512, 2) void gemm_argmin(
    const _Float16* __restrict__ zh, const _Float16* __restrict__ zl,
    const _Float16* __restrict__ eh, const _Float16* __restrict__ el,
    const float* __restrict__ ce, const float* __restrict__ cz,
    unsigned long long* __restrict__ keys) {
    extern __shared__ __align__(16) char lds_raw[];
    int tid = threadIdx.x;
    int bid = blockIdx.x;
    int swz = (bid & 7) * 256 + (bid >> 3);   // XCD-chunked, bijective (2048%8==0)
    int n0 = (swz & 15) * 128;                // code tile (16 n-tiles)
    int m0 = (swz >> 4) * 256;                // query-row tile (128 m-tiles)

    f32x4 acc0[4][4], acc1[4][4];
    #pragma unroll
    for (int a = 0; a < 4; ++a)
        #pragma unroll
        for (int b = 0; b < 4; ++b) { acc0[a][b] = (f32x4)0.0f; acc1[a][b] = (f32x4)0.0f; }

    int w = tid >> 6, l = tid & 63;
    int wm = (w >> 1) * 64;                   // 4 M-groups of 64 (256 rows)
    int wn = (w & 1) * 64;                    // 2 N-groups of 64 (128 rows)
    int fr = l & 15, fg = l >> 4;

    // LDS byte base (AS3 offset)
    u32 lbase = (u32)(size_t)(__attribute__((address_space(3))) char*)lds_raw;
    // per-thread fragment offsets within a buffer (bytes)
    u32 offAh[4], offBh[4];
    #pragma unroll
    for (int i = 0; i < 4; ++i) {
        int ra = wm + i * 16 + fr;
        offAh[i] = (u32)((ra * 4 + (fg ^ ((ra >> 1) & 3))) * 16);
        int rb = wn + i * 16 + fr;
        offBh[i] = (u32)(32768 + (rb * 4 + (fg ^ ((rb >> 1) & 3))) * 16);
    }
    // Al at +16384 from Ah; Bl at +8192 from Bh

    // staging: per wave per buffer 6 gloads (A q=0, A q=1, B), split in parts
    #define STAGE_P(buf, kc, part) do {                                           \
        char* sbase = lds_raw + (buf) * BUF_BYTES;                                \
        if ((part) < 2) {                                                         \
            int rA = 32 * w + 16 * (part) + (l >> 2);                             \
            int cA = (((l & 3) ^ ((rA >> 1) & 3)) << 3);                          \
            size_t oa = (size_t)(m0 + rA) * D_DIM + (kc) + cA;                    \
            int db = (32 * w + 16 * (part)) * 4;                                  \
            gload16(zh + oa, (h8*)sbase + db);                                    \
            gload16(zl + oa, (h8*)(sbase + 16384) + db);                          \
        } else {                                                                  \
            int rB = 16 * w + (l >> 2);                                           \
            int cB = (((l & 3) ^ ((rB >> 1) & 3)) << 3);                          \
            size_t ob = (size_t)(n0 + rB) * D_DIM + (kc) + cB;                    \
            gload16(eh + ob, (h8*)(sbase + 32768) + 16 * w * 4);                  \
            gload16(el + ob, (h8*)(sbase + 40960) + 16 * w * 4);                  \
        }                                                                         \
    } while (0)

    #define STAGE_ALL(buf, kc) do { STAGE_P(buf,kc,0); STAGE_P(buf,kc,1); STAGE_P(buf,kc,2); } while (0)

    #define MFMA_PHASE(AH, AL)                                                     \
        __builtin_amdgcn_s_setprio(1);                                             \
        _Pragma("unroll")                                                          \
        for (int nb = 0; nb < 4; ++nb) {                                           \
            acc0[mb][nb] = __builtin_amdgcn_mfma_f32_16x16x32_f16(AH, bhv[nb], acc0[mb][nb], 0, 0, 0); \
            acc1[mb][nb] = __builtin_amdgcn_mfma_f32_16x16x32_f16(AH, blv[nb], acc1[mb][nb], 0, 0, 0); \
            acc1[mb][nb] = __builtin_amdgcn_mfma_f32_16x16x32_f16(AL, bhv[nb], acc1[mb][nb], 0, 0, 0); \
        }                                                                          \
        __builtin_amdgcn_s_setprio(0);                                             \
        __builtin_amdgcn_sched_barrier(0);

    STAGE_ALL(0, 0);
    STAGE_ALL(1, 32);
    asm volatile("s_waitcnt vmcnt(6)" ::: "memory");   // buf0's 6 landed
    __builtin_amdgcn_s_barrier();
    __builtin_amdgcn_sched_barrier(0);

    int rd = 0;
    for (int t = 0; t < 16; ++t) {
        int wr = rd + 2; if (wr >= 3) wr -= 3;
        bool st = (t < 14);
        int kc2 = (t + 2) * 32;
        u32 rb = lbase + (u32)rd * BUF_BYTES;

        // issue all B reads (8), then A0 (2), stage, A1 (2)
        h8 bhv[4], blv[4];
        #pragma unroll
        for (int nb = 0; nb < 4; ++nb) {
            bhv[nb] = ds_read_h8(rb + offBh[nb]);
            blv[nb] = ds_read_h8(rb + offBh[nb] + 8192);
        }
        h8 a0h = ds_read_h8(rb + offAh[0]);
        h8 a0l = ds_read_h8(rb + offAh[0] + 16384);
        if (st) STAGE_P(wr, kc2, 0);
        h8 a1h = ds_read_h8(rb + offAh[1]);
        h8 a1l = ds_read_h8(rb + offAh[1] + 16384);
        LGKM(2);                                  // B + A0 ready, A1 in flight
        { int mb = 0; MFMA_PHASE(a0h, a0l); }

        h8 a2h = ds_read_h8(rb + offAh[2]);
        h8 a2l = ds_read_h8(rb + offAh[2] + 16384);
        if (st) STAGE_P(wr, kc2, 1);
        LGKM(2);                                  // A1 ready, A2 in flight
        { int mb = 1; MFMA_PHASE(a1h, a1l); }

        h8 a3h = ds_read_h8(rb + offAh[3]);
        h8 a3l = ds_read_h8(rb + offAh[3] + 16384);
        if (st) STAGE_P(wr, kc2, 2);
        LGKM(2);                                  // A2 ready, A3 in flight
        { int mb = 2; MFMA_PHASE(a2h, a2l); }

        LGKM(0);                                  // A3 ready
        { int mb = 3; MFMA_PHASE(a3h, a3l); }

        if (t < 15) {
            if (t < 14) asm volatile("s_waitcnt vmcnt(6)" ::: "memory");
            else        asm volatile("s_waitcnt vmcnt(0)" ::: "memory");
            __builtin_amdgcn_s_barrier();
            __builtin_amdgcn_sched_barrier(0);
        }
        if (++rd == 3) rd = 0;
    }
    #undef STAGE_P
    #undef STAGE_ALL
    #undef MFMA_PHASE

    // epilogue: dist = (ce+cz) - 2*dot, dot = acc0 + acc1*2^-11
    #pragma unroll
    for (int mb = 0; mb < 4; ++mb) {
        #pragma unroll
        for (int r = 0; r < 4; ++r) {
            int q = m0 + wm + mb * 16 + fg * 4 + r;
            float czq = cz[q];
            unsigned long long best = ~0ULL;
            #pragma unroll
            for (int nb = 0; nb < 4; ++nb) {
                int j = n0 + wn + nb * 16 + fr;
                float dotv = acc0[mb][nb][r] + acc1[mb][nb][r] * (1.0f / 2048.0f);
                float dist = (ce[j] + czq) - 2.0f * dotv;
                unsigned long long key =
                    ((unsigned long long)__float_as_uint(dist) << 32) | (unsigned)j;
                if (key < best) best = key;
            }
            #pragma unroll
            for (int sft = 1; sft < 16; sft <<= 1) {
                unsigned long long o = __shfl_xor(best, sft, 64);
                if (o < best) best = o;
            }
            if (fr == 0) atomicMin(keys + q, best);
        }
    }
}

// ---- gather + STE output + loss partials + histogram (1 wave per row) ----
__global__ void output_kernel(const float* __restrict__ x, const float* __restrict__ mu,
                              const float* __restrict__ s, const float* __restrict__ emb,
                              const unsigned long long* __restrict__ keys,
                              float* __restrict__ out, float* __restrict__ loss_part,
                              unsigned* __restrict__ hist) {
    int i = blockIdx.x * 4 + (threadIdx.x >> 6);
    int lane = threadIdx.x & 63;
    int n = i >> 10;
    unsigned idx = (unsigned)(keys[i] & 0xFFFFFFFFULL);
    float lsum = 0.f;
    #pragma unroll
    for (int c = 0; c < 2; ++c) {
        int d = c * 256 + lane * 4;
        float4 xv = *(const float4*)&x[(size_t)i * D_DIM + d];
        float4 mv = *(const float4*)&mu[n * D_DIM + d];
        float4 sv = *(const float4*)&s[n * D_DIM + d];
        float4 ev = *(const float4*)&emb[(size_t)idx * D_DIM + d];
        float z0 = (xv.x - mv.x) / sv.x;
        float z1 = (xv.y - mv.y) / sv.y;
        float z2 = (xv.z - mv.z) / sv.z;
        float z3 = (xv.w - mv.w) / sv.w;
        float o0 = ((z0 + (ev.x - z0)) + ev.x) * 0.5f;
        float o1 = ((z1 + (ev.y - z1)) + ev.y) * 0.5f;
        float o2 = ((z2 + (ev.z - z2)) + ev.z) * 0.5f;
        float o3 = ((z3 + (ev.w - z3)) + ev.w) * 0.5f;
        *(float4*)&out[(size_t)i * D_DIM + d] = make_float4(o0, o1, o2, o3);
        lsum += (z0 - ev.x) * (z0 - ev.x) + (z1 - ev.y) * (z1 - ev.y)
              + (z2 - ev.z) * (z2 - ev.z) + (z3 - ev.w) * (z3 - ev.w);
    }
    #pragma unroll
    for (int sft = 32; sft; sft >>= 1) lsum += __shfl_xor(lsum, sft, 64);
    __shared__ float ls[4];
    if (lane == 0) {
        ls[threadIdx.x >> 6] = lsum;
        atomicAdd(&hist[idx], 1u);   // scattered over 2048 bins: cheap
    }
    __syncthreads();
    if (threadIdx.x == 0)
        loss_part[blockIdx.x] = (ls[0] + ls[1]) + (ls[2] + ls[3]);
}

// ---- scalars: loss mean (from partials) + perplexity ----
__global__ void final_kernel(const unsigned* __restrict__ hist,
                             const float* __restrict__ loss_part, float* __restrict__ out) {
    float h = 0.f;
    for (int b = threadIdx.x; b < M_CODES; b += 256) {
        float p = (float)hist[b] * (1.0f / 32768.0f);
        h += p * logf(p + 1e-10f);
    }
    h = block_reduce_sum_256(h);
    float lsum = 0.f;
    for (int b = threadIdx.x; b < NT / 4; b += 256) lsum += loss_part[b];
    lsum = block_reduce_sum_256(lsum);
    if (threadIdx.x == 0) {
        out[TOTAL] = lsum * (1.0f / 16777216.0f);
        out[TOTAL + 1] = expf(-h);
    }
}

extern "C" void kernel_launch(void* const* d_in, const int* in_sizes, int n_in,
                              void* d_out, int out_size, void* d_ws, size_t ws_size,
                              hipStream_t stream) {
    (void)in_sizes; (void)n_in; (void)out_size; (void)ws_size;
    const float* x = (const float*)d_in[0];
    const float* emb = (const float*)d_in[1];
    float* out = (float*)d_out;
    char* ws = (char*)d_ws;
    float* mu   = (float*)(ws + WS_MU);
    float* s    = (float*)(ws + WS_S);
    float* cz   = (float*)(ws + WS_CZ);
    float* ce   = (float*)(ws + WS_CE);
    unsigned long long* keys = (unsigned long long*)(ws + WS_KEYS);
    _Float16* eh = (_Float16*)(ws + WS_EH);
    _Float16* el = (_Float16*)(ws + WS_EL);
    unsigned* hist = (unsigned*)(ws + WS_HIST);
    float* loss_part = (float*)(ws + WS_LPART);
    // z fp16 split staged in d_out (64MB exactly), overwritten by output_kernel
    _Float16* zh = (_Float16*)d_out;
    _Float16* zl = zh + TOTAL;

    // allow 144KB dynamic LDS (idempotent; not a stream op -> capture-safe)
    (void)hipFuncSetAttribute((const void*)gemm_argmin,
                              hipFuncAttributeMaxDynamicSharedMemorySize,
                              3 * BUF_BYTES);

    (void)hipMemsetAsync(ws + WS_KEYS, 0xFF, 262144, stream);
    (void)hipMemsetAsync(ws + WS_HIST, 0x00, 8192, stream);

    stats_kernel<<<dim3(8, 32), 256, 0, stream>>>(x, mu, s);
    codebook_kernel<<<M_CODES, 256, 0, stream>>>(emb, eh, el, ce);
    cz_split_kernel<<<NT / 4, 256, 0, stream>>>(x, mu, s, cz, zh, zl);
    gemm_argmin<<<2048, 512, 3 * BUF_BYTES, stream>>>(zh, zl, eh, el, ce, cz, keys);
    output_kernel<<<NT / 4, 256, 0, stream>>>(x, mu, s, emb, keys, out, loss_part, hist);
    final_kernel<<<1, 256, 0, stream>>>(hist, loss_part, out);
}